// Round 3
// baseline (2132.795 us; speedup 1.0000x reference)
//
#include <hip/hip_runtime.h>

#define DEV __device__ __forceinline__

typedef unsigned short u16;
typedef float f32x4 __attribute__((ext_vector_type(4)));
typedef __bf16 bf16x8 __attribute__((ext_vector_type(8)));

// ---------------- helpers ----------------
DEV u16 f2b(float f) {
    unsigned u = __builtin_bit_cast(unsigned, f);
    u += 0x7fffu + ((u >> 16) & 1u);   // RNE
    return (u16)(u >> 16);
}
DEV float b2f(u16 h) { return __builtin_bit_cast(float, (unsigned)h << 16); }
DEV float silu_(float v) { return v / (1.f + __expf(-v)); }

DEV void gload16(const void* g, void* l) {
    // async global->LDS, 16B/lane; LDS dest = wave-uniform base + lane*16
    __builtin_amdgcn_global_load_lds((const __attribute__((address_space(1))) unsigned int*)g,
                                     (__attribute__((address_space(3))) unsigned int*)l,
                                     16, 0, 0);
}

// ---------------- weight f32 -> bf16 ----------------
__global__ __launch_bounds__(256) void cvt_bf16_k(const float* __restrict__ in,
                                                  u16* __restrict__ out, int n4) {
    int i = blockIdx.x * 256 + threadIdx.x;
    if (i >= n4) return;
    float4 v = reinterpret_cast<const float4*>(in)[i];
    ushort4 o;
    o.x = f2b(v.x); o.y = f2b(v.y); o.z = f2b(v.z); o.w = f2b(v.w);
    reinterpret_cast<ushort4*>(out)[i] = o;
}

// ---------------- rmsnorm (D=1024), fp32 in -> bf16 out ----------------
__global__ __launch_bounds__(256) void rmsnorm_k(const float* __restrict__ x,
                                                 const float* __restrict__ w,
                                                 u16* __restrict__ out) {
    int row = blockIdx.x;
    int t = threadIdx.x;
    float4 v = reinterpret_cast<const float4*>(x + (size_t)row * 1024)[t];
    float s = v.x * v.x + v.y * v.y + v.z * v.z + v.w * v.w;
#pragma unroll
    for (int off = 32; off; off >>= 1) s += __shfl_xor(s, off);
    __shared__ float red[4];
    if ((t & 63) == 0) red[t >> 6] = s;
    __syncthreads();
    float tot = red[0] + red[1] + red[2] + red[3];
    float scale = rsqrtf(tot * (1.f / 1024.f) + 1e-6f);
    float4 wv = reinterpret_cast<const float4*>(w)[t];
    ushort4 o;
    o.x = f2b(v.x * wv.x * scale);
    o.y = f2b(v.y * wv.y * scale);
    o.z = f2b(v.z * wv.z * scale);
    o.w = f2b(v.w * wv.w * scale);
    reinterpret_cast<ushort4*>(out + (size_t)row * 1024)[t] = o;
}

// ---------------- GEMM: C[M,N] = A[M,K] * B[N,K]^T (bf16 in, fp32 acc) ----------------
// 128x128 tile, BK=32, 4 waves (2x2), each 64x64 via 4x4 x mfma_16x16x32_bf16.
// EPI: 0 = store bf16
//      1 = softplus(acc + bias[col]) -> bf16
//      2 = acc + residf32[row,col]   -> f32
//      4 = silu(auxbf16[row,col]) * acc -> bf16   (aux may alias C, same-idx only)
template <int EPI>
__global__ __launch_bounds__(256) void gemm_bt(
    const u16* __restrict__ A, int lda,
    const u16* __restrict__ B, int ldb,
    void* C, int ldc,
    int N, int K,
    const float* __restrict__ bias,
    const void* aux, int ldaux) {
    __shared__ u16 lsA[128 * 32];
    __shared__ u16 lsB[128 * 32];
    const int t = threadIdx.x;
    const int l = t & 63, w = t >> 6;
    const int m0 = blockIdx.x * 128, n0 = blockIdx.y * 128;
    const int wm = w >> 1, wn = w & 1;
    const int lrow = l & 15, lk8 = (l >> 4) * 8;

    // staging coords: each of 4 waves covers 16 rows x 32 cols per call
    const int sr = w * 16 + (l >> 2);   // 0..63
    const int sc = (l & 3) * 8;         // 0,8,16,24
    const u16* gA0 = A + (size_t)(m0 + sr) * lda + sc;
    const u16* gA1 = gA0 + (size_t)64 * lda;
    int nr0 = n0 + sr;      if (nr0 > N - 1) nr0 = N - 1;
    int nr1 = n0 + 64 + sr; if (nr1 > N - 1) nr1 = N - 1;
    const u16* gB0 = B + (size_t)nr0 * ldb + sc;
    const u16* gB1 = B + (size_t)nr1 * ldb + sc;
    u16* ldsA0 = &lsA[w * 512];
    u16* ldsA1 = &lsA[2048 + w * 512];
    u16* ldsB0 = &lsB[w * 512];
    u16* ldsB1 = &lsB[2048 + w * 512];

    f32x4 acc[4][4];
#pragma unroll
    for (int i = 0; i < 4; ++i)
#pragma unroll
        for (int j = 0; j < 4; ++j) acc[i][j] = (f32x4){0.f, 0.f, 0.f, 0.f};

    for (int k0 = 0; k0 < K; k0 += 32) {
        gload16(gA0 + k0, ldsA0);
        gload16(gA1 + k0, ldsA1);
        gload16(gB0 + k0, ldsB0);
        gload16(gB1 + k0, ldsB1);
        __syncthreads();
        bf16x8 af[4], bfr[4];
#pragma unroll
        for (int i = 0; i < 4; ++i)
            af[i] = *reinterpret_cast<const bf16x8*>(&lsA[(wm * 64 + i * 16 + lrow) * 32 + lk8]);
#pragma unroll
        for (int j = 0; j < 4; ++j)
            bfr[j] = *reinterpret_cast<const bf16x8*>(&lsB[(wn * 64 + j * 16 + lrow) * 32 + lk8]);
#pragma unroll
        for (int i = 0; i < 4; ++i)
#pragma unroll
            for (int j = 0; j < 4; ++j)
                acc[i][j] = __builtin_amdgcn_mfma_f32_16x16x32_bf16(af[i], bfr[j], acc[i][j], 0, 0, 0);
        __syncthreads();
    }

    // C/D layout: col = lane&15, row = (lane>>4)*4 + reg
    const int rbase = m0 + wm * 64 + (l >> 4) * 4;
    const int cbase = n0 + wn * 64 + (l & 15);
#pragma unroll
    for (int i = 0; i < 4; ++i) {
#pragma unroll
        for (int j = 0; j < 4; ++j) {
            int col = cbase + j * 16;
            if (col >= N) continue;
#pragma unroll
            for (int r = 0; r < 4; ++r) {
                int row = rbase + i * 16 + r;
                float v = acc[i][j][r];
                size_t idx = (size_t)row * ldc + col;
                if constexpr (EPI == 0) {
                    ((u16*)C)[idx] = f2b(v);
                } else if constexpr (EPI == 1) {
                    float z = v + bias[col];
                    float sp = z > 20.f ? z : log1pf(__expf(z));
                    ((u16*)C)[idx] = f2b(sp);
                } else if constexpr (EPI == 2) {
                    ((float*)C)[idx] = v + ((const float*)aux)[(size_t)row * ldaux + col];
                } else if constexpr (EPI == 4) {
                    float g = b2f(((const u16*)aux)[(size_t)row * ldaux + col]);
                    ((u16*)C)[idx] = f2b(silu_(g) * v);
                }
            }
        }
    }
}

// ---------------- causal depthwise conv (width 4) + bias + silu ----------------
// xraw: (B*L, 2048) bf16 -> xin: (B*L, 2048) bf16
__global__ __launch_bounds__(256) void conv_k(const u16* __restrict__ xraw,
                                              const float* __restrict__ cw,
                                              const float* __restrict__ cb,
                                              u16* __restrict__ xin) {
    size_t idx = (size_t)blockIdx.x * 256 + threadIdx.x;
    if (idx >= (size_t)4096 * 2048) return;
    int d = (int)(idx & 2047);
    int m = (int)(idx >> 11);        // b*2048 + l
    int lpos = m & 2047, b = m >> 11;
    float acc = cb[d];
#pragma unroll
    for (int j = 0; j < 4; ++j) {
        int lj = lpos - 3 + j;
        if (lj >= 0)
            acc += b2f(xraw[((size_t)(b * 2048 + lj) << 11) + d]) * cw[d * 4 + j];
    }
    xin[idx] = f2b(silu_(acc));
}

// ---------------- selective scan ----------------
// lane: n = l&15 (state), dsub = l>>4; wave handles 4 channels; block = 16 channels
// grid = B * (2048/16) = 256 blocks
__global__ __launch_bounds__(256) void scan_k(const u16* __restrict__ delta,
                                              const u16* __restrict__ xdbl,
                                              const u16* __restrict__ xin,
                                              const u16* __restrict__ zb,
                                              const float* __restrict__ A_log,
                                              const float* __restrict__ Dv,
                                              u16* __restrict__ y2) {
    int t = threadIdx.x;
    int l = t & 63, w = t >> 6;
    int n = l & 15, dsub = l >> 4;
    int blk = blockIdx.x;
    int b = blk >> 7;
    int d = (blk & 127) * 16 + w * 4 + dsub;
    float Af = -__expf(A_log[d * 16 + n]);
    float Dd = Dv[d];
    float h = 0.f;
    const size_t rbase = (size_t)b * 2048;
#pragma unroll 4
    for (int tt = 0; tt < 2048; ++tt) {
        size_t r = rbase + tt;
        float dlt = b2f(delta[(r << 11) + d]);
        float xv  = b2f(xin[(r << 11) + d]);
        float Bt  = b2f(xdbl[r * 96 + 64 + n]);
        float Ct  = b2f(xdbl[r * 96 + 80 + n]);
        float dA = __expf(dlt * Af);
        h = dA * h + (dlt * xv) * Bt;
        float yp = h * Ct;
        yp += __shfl_xor(yp, 1);
        yp += __shfl_xor(yp, 2);
        yp += __shfl_xor(yp, 4);
        yp += __shfl_xor(yp, 8);
        if (n == 0) {
            float zv = b2f(zb[(r << 11) + d]);
            float y = yp + xv * Dd;
            y2[(r << 11) + d] = f2b(y * silu_(zv));
        }
    }
}

// ---------------- launch ----------------
extern "C" void kernel_launch(void* const* d_in, const int* in_sizes, int n_in,
                              void* d_out, int out_size, void* d_ws, size_t ws_size,
                              hipStream_t stream) {
    const float* x         = (const float*)d_in[0];
    const float* n1w       = (const float*)d_in[1];
    const float* n2w       = (const float*)d_in[2];
    const float* w_inproj  = (const float*)d_in[3];
    const float* conv_w    = (const float*)d_in[4];
    const float* conv_b    = (const float*)d_in[5];
    const float* w_xproj   = (const float*)d_in[6];
    const float* w_dtproj  = (const float*)d_in[7];
    const float* dt_b      = (const float*)d_in[8];
    const float* A_log     = (const float*)d_in[9];
    const float* Dv        = (const float*)d_in[10];
    const float* w_outproj = (const float*)d_in[11];
    const float* w1        = (const float*)d_in[12];
    const float* w3        = (const float*)d_in[13];
    const float* w2        = (const float*)d_in[14];

    // ---- workspace map (peak 84,672,512 B ~= 80.8 MiB) ----
    // wbuf is a single 8MB bf16 weight scratch, re-converted before each GEMM
    // (stream-ordered, so overwrite waits for the previous GEMM's reads).
    char* ws = (char*)d_ws;
    u16* wbuf    = (u16*)(ws + 0);          // max 4096x1024 bf16 = 8 MiB
    u16* h_bf    = (u16*)(ws + 8388608);    // 4096x1024 bf16 (h1, later h2)
    u16* xraw_bf = (u16*)(ws + 16777216);   // 4096x2048 (pre-conv); later y2; later g1 (spans z too)
    u16* z_bf    = (u16*)(ws + 33554432);   // 4096x2048 (gate)
    u16* xin_bf  = (u16*)(ws + 50331648);   // 4096x2048
    u16* dlt_bf  = (u16*)(ws + 67108864);   // 4096x2048; later x2_f (f32)
    u16* xdbl_bf = (u16*)(ws + 83886080);   // 4096x96 -> ends 84,672,512
    u16* y2_bf   = xraw_bf;                 // xraw dead after conv
    float* x2_f  = (float*)(ws + 67108864); // dlt+... dead after scan
    u16* g1_bf   = xraw_bf;                 // 4096x4096: y2 dead after out_proj GEMM, z dead after scan
    u16* act_bf  = g1_bf;                   // in-place over g1 (EPI4 same-idx)

    auto cvt = [&](const float* src, int n) {
        int n4 = n >> 2;
        cvt_bf16_k<<<(n4 + 255) / 256, 256, 0, stream>>>(src, wbuf, n4);
    };

    // h1 = rmsnorm(x)
    rmsnorm_k<<<4096, 256, 0, stream>>>(x, n1w, h_bf);
    // xraw = h1 @ in_proj[0:2048]^T ; z = h1 @ in_proj[2048:4096]^T
    cvt(w_inproj, 4096 * 1024);
    gemm_bt<0><<<dim3(32, 16), 256, 0, stream>>>(h_bf, 1024, wbuf, 1024, xraw_bf, 2048,
                                                 2048, 1024, nullptr, nullptr, 0);
    gemm_bt<0><<<dim3(32, 16), 256, 0, stream>>>(h_bf, 1024, wbuf + (size_t)2048 * 1024, 1024,
                                                 z_bf, 2048, 2048, 1024, nullptr, nullptr, 0);
    // xin = silu(causal_conv(xraw) + b)
    conv_k<<<32768, 256, 0, stream>>>(xraw_bf, conv_w, conv_b, xin_bf);
    // x_dbl = xin @ x_proj^T  (N=96, K=2048)
    cvt(w_xproj, 96 * 2048);
    gemm_bt<0><<<dim3(32, 1), 256, 0, stream>>>(xin_bf, 2048, wbuf, 2048, xdbl_bf, 96,
                                                96, 2048, nullptr, nullptr, 0);
    // delta = softplus(x_dbl[:, :64] @ dt_proj^T + dt_b)  (N=2048, K=64)
    cvt(w_dtproj, 2048 * 64);
    gemm_bt<1><<<dim3(32, 16), 256, 0, stream>>>(xdbl_bf, 96, wbuf, 64, dlt_bf, 2048,
                                                 2048, 64, dt_b, nullptr, 0);
    // selective scan + (+xin*D) * silu(z)  -> y2 (overlays xraw)
    scan_k<<<256, 256, 0, stream>>>(dlt_bf, xdbl_bf, xin_bf, z_bf, A_log, Dv, y2_bf);
    // x2 = x + y2 @ out_proj^T  (N=1024, K=2048) -> f32 (overlays dlt)
    cvt(w_outproj, 1024 * 2048);
    gemm_bt<2><<<dim3(32, 8), 256, 0, stream>>>(y2_bf, 2048, wbuf, 2048, x2_f, 1024,
                                                1024, 2048, nullptr, x, 1024);
    // h2 = rmsnorm(x2)
    rmsnorm_k<<<4096, 256, 0, stream>>>(x2_f, n2w, h_bf);
    // g1 = h2 @ w1^T ; act = silu(g1) * (h2 @ w3^T)   (act in-place over g1)
    cvt(w1, 4096 * 1024);
    gemm_bt<0><<<dim3(32, 32), 256, 0, stream>>>(h_bf, 1024, wbuf, 1024, g1_bf, 4096,
                                                 4096, 1024, nullptr, nullptr, 0);
    cvt(w3, 4096 * 1024);
    gemm_bt<4><<<dim3(32, 32), 256, 0, stream>>>(h_bf, 1024, wbuf, 1024, act_bf, 4096,
                                                 4096, 1024, nullptr, g1_bf, 4096);
    // out = x2 + act @ w2^T  (N=1024, K=4096) -> f32 d_out
    cvt(w2, 1024 * 4096);
    gemm_bt<2><<<dim3(32, 8), 256, 0, stream>>>(act_bf, 4096, wbuf, 4096, (float*)d_out, 1024,
                                                1024, 4096, nullptr, x2_f, 1024);
}

// Round 4
// 750.972 us; speedup vs baseline: 2.8400x; 2.8400x over previous
//
#include <hip/hip_runtime.h>

#define DEV __device__ __forceinline__

typedef unsigned short u16;
typedef float f32x4 __attribute__((ext_vector_type(4)));
typedef __bf16 bf16x8 __attribute__((ext_vector_type(8)));

#define CHUNK 64
#define NCH 32   // 2048 / CHUNK

// ---------------- helpers ----------------
DEV u16 f2b(float f) {
    unsigned u = __builtin_bit_cast(unsigned, f);
    u += 0x7fffu + ((u >> 16) & 1u);   // RNE
    return (u16)(u >> 16);
}
DEV float b2f(u16 h) { return __builtin_bit_cast(float, (unsigned)h << 16); }
DEV float silu_(float v) { return v / (1.f + __expf(-v)); }
DEV float b2f_lo(unsigned w) { return __builtin_bit_cast(float, w << 16); }
DEV float b2f_hi(unsigned w) { return __builtin_bit_cast(float, w & 0xffff0000u); }
DEV void unpack8(uint4 w, float* f) {
    f[0] = b2f_lo(w.x); f[1] = b2f_hi(w.x);
    f[2] = b2f_lo(w.y); f[3] = b2f_hi(w.y);
    f[4] = b2f_lo(w.z); f[5] = b2f_hi(w.z);
    f[6] = b2f_lo(w.w); f[7] = b2f_hi(w.w);
}

DEV void gload16(const void* g, void* l) {
    // async global->LDS, 16B/lane; LDS dest = wave-uniform base + lane*16
    __builtin_amdgcn_global_load_lds((const __attribute__((address_space(1))) unsigned int*)g,
                                     (__attribute__((address_space(3))) unsigned int*)l,
                                     16, 0, 0);
}

// ---------------- weight f32 -> bf16 ----------------
__global__ __launch_bounds__(256) void cvt_bf16_k(const float* __restrict__ in,
                                                  u16* __restrict__ out, int n4) {
    int i = blockIdx.x * 256 + threadIdx.x;
    if (i >= n4) return;
    float4 v = reinterpret_cast<const float4*>(in)[i];
    ushort4 o;
    o.x = f2b(v.x); o.y = f2b(v.y); o.z = f2b(v.z); o.w = f2b(v.w);
    reinterpret_cast<ushort4*>(out)[i] = o;
}

// ---------------- rmsnorm (D=1024), fp32 in -> bf16 out ----------------
__global__ __launch_bounds__(256) void rmsnorm_k(const float* __restrict__ x,
                                                 const float* __restrict__ w,
                                                 u16* __restrict__ out) {
    int row = blockIdx.x;
    int t = threadIdx.x;
    float4 v = reinterpret_cast<const float4*>(x + (size_t)row * 1024)[t];
    float s = v.x * v.x + v.y * v.y + v.z * v.z + v.w * v.w;
#pragma unroll
    for (int off = 32; off; off >>= 1) s += __shfl_xor(s, off);
    __shared__ float red[4];
    if ((t & 63) == 0) red[t >> 6] = s;
    __syncthreads();
    float tot = red[0] + red[1] + red[2] + red[3];
    float scale = rsqrtf(tot * (1.f / 1024.f) + 1e-6f);
    float4 wv = reinterpret_cast<const float4*>(w)[t];
    ushort4 o;
    o.x = f2b(v.x * wv.x * scale);
    o.y = f2b(v.y * wv.y * scale);
    o.z = f2b(v.z * wv.z * scale);
    o.w = f2b(v.w * wv.w * scale);
    reinterpret_cast<ushort4*>(out + (size_t)row * 1024)[t] = o;
}

// ---------------- GEMM: C[M,N] = A[M,K] * B[N,K]^T (bf16 in, fp32 acc) ----------------
// 128x128 tile, BK=32, 4 waves (2x2), each 64x64 via 4x4 x mfma_16x16x32_bf16.
// EPI: 0 = store bf16
//      1 = softplus(acc + bias[col]) -> bf16
//      2 = acc + residf32[row,col]   -> f32
//      4 = silu(auxbf16[row,col]) * acc -> bf16   (aux may alias C, same-idx only)
template <int EPI>
__global__ __launch_bounds__(256) void gemm_bt(
    const u16* __restrict__ A, int lda,
    const u16* __restrict__ B, int ldb,
    void* C, int ldc,
    int N, int K,
    const float* __restrict__ bias,
    const void* aux, int ldaux) {
    __shared__ u16 lsA[128 * 32];
    __shared__ u16 lsB[128 * 32];
    const int t = threadIdx.x;
    const int l = t & 63, w = t >> 6;
    const int m0 = blockIdx.x * 128, n0 = blockIdx.y * 128;
    const int wm = w >> 1, wn = w & 1;
    const int lrow = l & 15, lk8 = (l >> 4) * 8;

    const int sr = w * 16 + (l >> 2);   // 0..63
    const int sc = (l & 3) * 8;         // 0,8,16,24
    const u16* gA0 = A + (size_t)(m0 + sr) * lda + sc;
    const u16* gA1 = gA0 + (size_t)64 * lda;
    int nr0 = n0 + sr;      if (nr0 > N - 1) nr0 = N - 1;
    int nr1 = n0 + 64 + sr; if (nr1 > N - 1) nr1 = N - 1;
    const u16* gB0 = B + (size_t)nr0 * ldb + sc;
    const u16* gB1 = B + (size_t)nr1 * ldb + sc;
    u16* ldsA0 = &lsA[w * 512];
    u16* ldsA1 = &lsA[2048 + w * 512];
    u16* ldsB0 = &lsB[w * 512];
    u16* ldsB1 = &lsB[2048 + w * 512];

    f32x4 acc[4][4];
#pragma unroll
    for (int i = 0; i < 4; ++i)
#pragma unroll
        for (int j = 0; j < 4; ++j) acc[i][j] = (f32x4){0.f, 0.f, 0.f, 0.f};

    for (int k0 = 0; k0 < K; k0 += 32) {
        gload16(gA0 + k0, ldsA0);
        gload16(gA1 + k0, ldsA1);
        gload16(gB0 + k0, ldsB0);
        gload16(gB1 + k0, ldsB1);
        __syncthreads();
        bf16x8 af[4], bfr[4];
#pragma unroll
        for (int i = 0; i < 4; ++i)
            af[i] = *reinterpret_cast<const bf16x8*>(&lsA[(wm * 64 + i * 16 + lrow) * 32 + lk8]);
#pragma unroll
        for (int j = 0; j < 4; ++j)
            bfr[j] = *reinterpret_cast<const bf16x8*>(&lsB[(wn * 64 + j * 16 + lrow) * 32 + lk8]);
#pragma unroll
        for (int i = 0; i < 4; ++i)
#pragma unroll
            for (int j = 0; j < 4; ++j)
                acc[i][j] = __builtin_amdgcn_mfma_f32_16x16x32_bf16(af[i], bfr[j], acc[i][j], 0, 0, 0);
        __syncthreads();
    }

    // C/D layout: col = lane&15, row = (lane>>4)*4 + reg
    const int rbase = m0 + wm * 64 + (l >> 4) * 4;
    const int cbase = n0 + wn * 64 + (l & 15);
#pragma unroll
    for (int i = 0; i < 4; ++i) {
#pragma unroll
        for (int j = 0; j < 4; ++j) {
            int col = cbase + j * 16;
            if (col >= N) continue;
#pragma unroll
            for (int r = 0; r < 4; ++r) {
                int row = rbase + i * 16 + r;
                float v = acc[i][j][r];
                size_t idx = (size_t)row * ldc + col;
                if constexpr (EPI == 0) {
                    ((u16*)C)[idx] = f2b(v);
                } else if constexpr (EPI == 1) {
                    float z = v + bias[col];
                    float sp = z > 20.f ? z : log1pf(__expf(z));
                    ((u16*)C)[idx] = f2b(sp);
                } else if constexpr (EPI == 2) {
                    ((float*)C)[idx] = v + ((const float*)aux)[(size_t)row * ldaux + col];
                } else if constexpr (EPI == 4) {
                    float g = b2f(((const u16*)aux)[(size_t)row * ldaux + col]);
                    ((u16*)C)[idx] = f2b(silu_(g) * v);
                }
            }
        }
    }
}

// ---------------- causal depthwise conv (width 4) + bias + silu ----------------
__global__ __launch_bounds__(256) void conv_k(const u16* __restrict__ xraw,
                                              const float* __restrict__ cw,
                                              const float* __restrict__ cb,
                                              u16* __restrict__ xin) {
    size_t idx = (size_t)blockIdx.x * 256 + threadIdx.x;
    if (idx >= (size_t)4096 * 2048) return;
    int d = (int)(idx & 2047);
    int m = (int)(idx >> 11);        // b*2048 + l
    int lpos = m & 2047, b = m >> 11;
    float acc = cb[d];
#pragma unroll
    for (int j = 0; j < 4; ++j) {
        int lj = lpos - 3 + j;
        if (lj >= 0)
            acc += b2f(xraw[((size_t)(b * 2048 + lj) << 11) + d]) * cw[d * 4 + j];
    }
    xin[idx] = f2b(silu_(acc));
}

// ---------------- chunked selective scan ----------------
// P1: per-chunk local scan (h starts at 0), emit final state + sum(delta).
// Thread owns channel d; 16 states in registers; B staged in LDS.
// grid = B * NCH * 8 = 512 blocks; blk = b*256 + c*8 + g
__global__ __launch_bounds__(256) void scan_p1(const u16* __restrict__ dlt,
                                               const u16* __restrict__ xin,
                                               const u16* __restrict__ xdbl,
                                               const float* __restrict__ A_log,
                                               float* __restrict__ hfin,
                                               float* __restrict__ sdlt) {
    int blk = blockIdx.x;
    int g = blk & 7, c = (blk >> 3) & 31, b = blk >> 8;
    int d = g * 256 + threadIdx.x;
    __shared__ u16 bc[CHUNK * 32];
    {
        int i = threadIdx.x;
        int r = i >> 2, q = i & 3;
        const u16* src = xdbl + ((size_t)(b * 2048 + c * CHUNK + r) * 96 + 64 + q * 8);
        *reinterpret_cast<uint4*>(&bc[r * 32 + q * 8]) = *reinterpret_cast<const uint4*>(src);
    }
    __syncthreads();
    float A2[16];
#pragma unroll
    for (int n = 0; n < 16; ++n) A2[n] = -__expf(A_log[d * 16 + n]) * 1.44269504f;
    float h[16];
#pragma unroll
    for (int n = 0; n < 16; ++n) h[n] = 0.f;
    float S = 0.f;
    size_t base = ((size_t)(b * 2048 + c * CHUNK) << 11) + d;
#pragma unroll 4
    for (int t = 0; t < CHUNK; ++t) {
        float dl = b2f(dlt[base + ((size_t)t << 11)]);
        float xv = b2f(xin[base + ((size_t)t << 11)]);
        S += dl;
        float dx = dl * xv;
        float Bv[16];
        unpack8(*reinterpret_cast<const uint4*>(&bc[t * 32]), Bv);
        unpack8(*reinterpret_cast<const uint4*>(&bc[t * 32 + 8]), Bv + 8);
#pragma unroll
        for (int n = 0; n < 16; ++n)
            h[n] = __builtin_amdgcn_exp2f(dl * A2[n]) * h[n] + dx * Bv[n];
    }
    float* hf = hfin + ((size_t)((b * NCH + c) * 2048 + d) << 4);
#pragma unroll
    for (int n = 0; n < 4; ++n)
        reinterpret_cast<float4*>(hf)[n] = (float4){h[4*n], h[4*n+1], h[4*n+2], h[4*n+3]};
    sdlt[(b * NCH + c) * 2048 + d] = S;
}

// P2: carry propagation across chunks. thread = (b, d, n); grid = B*D*16/256 = 256 blocks
__global__ __launch_bounds__(256) void scan_p2(const float* __restrict__ hfin,
                                               const float* __restrict__ sdlt,
                                               const float* __restrict__ A_log,
                                               float* __restrict__ hini) {
    int t = blockIdx.x * 256 + threadIdx.x;
    int n = t & 15, d = (t >> 4) & 2047, b = t >> 15;
    float A2 = -__expf(A_log[d * 16 + n]) * 1.44269504f;
    float h = 0.f;
    for (int c = 0; c < NCH; ++c) {
        size_t idx = ((size_t)((b * NCH + c) * 2048 + d) << 4) + n;
        hini[idx] = h;
        float P = __builtin_amdgcn_exp2f(A2 * sdlt[(b * NCH + c) * 2048 + d]);
        h = P * h + hfin[idx];
    }
}

// P3: re-run chunks from propagated initial state; fuse y = sum(h*C) + x*D, * silu(z)
__global__ __launch_bounds__(256) void scan_p3(const u16* __restrict__ dlt,
                                               const u16* __restrict__ xin,
                                               const u16* __restrict__ xdbl,
                                               const u16* __restrict__ zb,
                                               const float* __restrict__ A_log,
                                               const float* __restrict__ Dv,
                                               const float* __restrict__ hini,
                                               u16* __restrict__ y2) {
    int blk = blockIdx.x;
    int g = blk & 7, c = (blk >> 3) & 31, b = blk >> 8;
    int d = g * 256 + threadIdx.x;
    __shared__ u16 bc[CHUNK * 32];
    {
        int i = threadIdx.x;
        int r = i >> 2, q = i & 3;
        const u16* src = xdbl + ((size_t)(b * 2048 + c * CHUNK + r) * 96 + 64 + q * 8);
        *reinterpret_cast<uint4*>(&bc[r * 32 + q * 8]) = *reinterpret_cast<const uint4*>(src);
    }
    __syncthreads();
    float A2[16];
#pragma unroll
    for (int n = 0; n < 16; ++n) A2[n] = -__expf(A_log[d * 16 + n]) * 1.44269504f;
    float h[16];
    const float* hi = hini + ((size_t)((b * NCH + c) * 2048 + d) << 4);
#pragma unroll
    for (int n = 0; n < 4; ++n) {
        float4 v = reinterpret_cast<const float4*>(hi)[n];
        h[4*n] = v.x; h[4*n+1] = v.y; h[4*n+2] = v.z; h[4*n+3] = v.w;
    }
    float Dd = Dv[d];
    size_t base = ((size_t)(b * 2048 + c * CHUNK) << 11) + d;
#pragma unroll 4
    for (int t = 0; t < CHUNK; ++t) {
        float dl = b2f(dlt[base + ((size_t)t << 11)]);
        float xv = b2f(xin[base + ((size_t)t << 11)]);
        float zv = b2f(zb[base + ((size_t)t << 11)]);
        float dx = dl * xv;
        float Bv[16], Cv[16];
        unpack8(*reinterpret_cast<const uint4*>(&bc[t * 32]), Bv);
        unpack8(*reinterpret_cast<const uint4*>(&bc[t * 32 + 8]), Bv + 8);
        unpack8(*reinterpret_cast<const uint4*>(&bc[t * 32 + 16]), Cv);
        unpack8(*reinterpret_cast<const uint4*>(&bc[t * 32 + 24]), Cv + 8);
        float y = 0.f;
#pragma unroll
        for (int n = 0; n < 16; ++n) {
            h[n] = __builtin_amdgcn_exp2f(dl * A2[n]) * h[n] + dx * Bv[n];
            y += h[n] * Cv[n];
        }
        y = (y + xv * Dd) * silu_(zv);
        y2[base + ((size_t)t << 11)] = f2b(y);
    }
}

// wait: bc staging covers cols 64..96 (B at 0..16, C at 16..32 within bc)

// ---------------- launch ----------------
extern "C" void kernel_launch(void* const* d_in, const int* in_sizes, int n_in,
                              void* d_out, int out_size, void* d_ws, size_t ws_size,
                              hipStream_t stream) {
    const float* x         = (const float*)d_in[0];
    const float* n1w       = (const float*)d_in[1];
    const float* n2w       = (const float*)d_in[2];
    const float* w_inproj  = (const float*)d_in[3];
    const float* conv_w    = (const float*)d_in[4];
    const float* conv_b    = (const float*)d_in[5];
    const float* x_projw   = (const float*)d_in[6];
    const float* w_dtproj  = (const float*)d_in[7];
    const float* dt_b      = (const float*)d_in[8];
    const float* A_log     = (const float*)d_in[9];
    const float* Dv        = (const float*)d_in[10];
    const float* w_outproj = (const float*)d_in[11];
    const float* w1        = (const float*)d_in[12];
    const float* w3        = (const float*)d_in[13];
    const float* w2        = (const float*)d_in[14];

    // ---- workspace map (peak 85,196,800 B ~= 81.3 MiB) ----
    char* ws = (char*)d_ws;
    u16* wbuf    = (u16*)(ws + 0);          // 8 MiB weight scratch; hfin during scan
    u16* h_bf    = (u16*)(ws + 8388608);    // 4096x1024 bf16 (h1/h2); hini during scan
    u16* xraw_bf = (u16*)(ws + 16777216);   // 4096x2048 (pre-conv); later y2; later g1
    u16* z_bf    = (u16*)(ws + 33554432);   // 4096x2048 (gate)
    u16* xin_bf  = (u16*)(ws + 50331648);   // 4096x2048
    u16* dlt_bf  = (u16*)(ws + 67108864);   // 4096x2048; later x2_f (f32)
    u16* xdbl_bf = (u16*)(ws + 83886080);   // 4096x96 -> ends 84,672,512
    float* sdlt  = (float*)(ws + 84672512); // B*NCH*2048 f32 = 512 KiB -> ends 85,196,800
    float* hfin  = (float*)wbuf;            // B*NCH*2048*16 f32 = 8 MiB exactly
    float* hini  = (float*)h_bf;            // 8 MiB (h1 dead during scan)
    u16* y2_bf   = xraw_bf;                 // xraw dead after conv
    float* x2_f  = (float*)(ws + 67108864); // dlt dead after scan
    u16* g1_bf   = xraw_bf;                 // y2+z dead after out_proj/scan
    u16* act_bf  = g1_bf;                   // in-place over g1 (EPI4 same-idx)

    auto cvt = [&](const float* src, int n) {
        int n4 = n >> 2;
        cvt_bf16_k<<<(n4 + 255) / 256, 256, 0, stream>>>(src, wbuf, n4);
    };

    // h1 = rmsnorm(x)
    rmsnorm_k<<<4096, 256, 0, stream>>>(x, n1w, h_bf);
    // xraw = h1 @ in_proj[0:2048]^T ; z = h1 @ in_proj[2048:4096]^T
    cvt(w_inproj, 4096 * 1024);
    gemm_bt<0><<<dim3(32, 16), 256, 0, stream>>>(h_bf, 1024, wbuf, 1024, xraw_bf, 2048,
                                                 2048, 1024, nullptr, nullptr, 0);
    gemm_bt<0><<<dim3(32, 16), 256, 0, stream>>>(h_bf, 1024, wbuf + (size_t)2048 * 1024, 1024,
                                                 z_bf, 2048, 2048, 1024, nullptr, nullptr, 0);
    // xin = silu(causal_conv(xraw) + b)
    conv_k<<<32768, 256, 0, stream>>>(xraw_bf, conv_w, conv_b, xin_bf);
    // x_dbl = xin @ x_proj^T  (N=96, K=2048)
    cvt(x_projw, 96 * 2048);
    gemm_bt<0><<<dim3(32, 1), 256, 0, stream>>>(xin_bf, 2048, wbuf, 2048, xdbl_bf, 96,
                                                96, 2048, nullptr, nullptr, 0);
    // delta = softplus(x_dbl[:, :64] @ dt_proj^T + dt_b)  (N=2048, K=64)
    cvt(w_dtproj, 2048 * 64);
    gemm_bt<1><<<dim3(32, 16), 256, 0, stream>>>(xdbl_bf, 96, wbuf, 64, dlt_bf, 2048,
                                                 2048, 64, dt_b, nullptr, 0);
    // chunked selective scan -> y2 (overlays xraw)
    scan_p1<<<512, 256, 0, stream>>>(dlt_bf, xin_bf, xdbl_bf, A_log, hfin, sdlt);
    scan_p2<<<256, 256, 0, stream>>>(hfin, sdlt, A_log, hini);
    scan_p3<<<512, 256, 0, stream>>>(dlt_bf, xin_bf, xdbl_bf, z_bf, A_log, Dv, hini, y2_bf);
    // x2 = x + y2 @ out_proj^T  (N=1024, K=2048) -> f32 (overlays dlt)
    cvt(w_outproj, 1024 * 2048);
    gemm_bt<2><<<dim3(32, 8), 256, 0, stream>>>(y2_bf, 2048, wbuf, 2048, x2_f, 1024,
                                                1024, 2048, nullptr, x, 1024);
    // h2 = rmsnorm(x2)
    rmsnorm_k<<<4096, 256, 0, stream>>>(x2_f, n2w, h_bf);
    // g1 = h2 @ w1^T ; act = silu(g1) * (h2 @ w3^T)   (act in-place over g1)
    cvt(w1, 4096 * 1024);
    gemm_bt<0><<<dim3(32, 32), 256, 0, stream>>>(h_bf, 1024, wbuf, 1024, g1_bf, 4096,
                                                 4096, 1024, nullptr, nullptr, 0);
    cvt(w3, 4096 * 1024);
    gemm_bt<4><<<dim3(32, 32), 256, 0, stream>>>(h_bf, 1024, wbuf, 1024, act_bf, 4096,
                                                 4096, 1024, nullptr, g1_bf, 4096);
    // out = x2 + act @ w2^T  (N=1024, K=4096) -> f32 d_out
    cvt(w2, 1024 * 4096);
    gemm_bt<2><<<dim3(32, 8), 256, 0, stream>>>(act_bf, 4096, wbuf, 4096, (float*)d_out, 1024,
                                                1024, 4096, nullptr, x2_f, 1024);
}

// Round 6
// 705.803 us; speedup vs baseline: 3.0218x; 1.0640x over previous
//
#include <hip/hip_runtime.h>

#define DEV __device__ __forceinline__

typedef unsigned short u16;
typedef float f32x4 __attribute__((ext_vector_type(4)));
typedef __bf16 bf16x8 __attribute__((ext_vector_type(8)));

#define CHUNK 64
#define NCH 32   // 2048 / CHUNK

// ---------------- helpers ----------------
DEV u16 f2b(float f) {
    unsigned u = __builtin_bit_cast(unsigned, f);
    u += 0x7fffu + ((u >> 16) & 1u);   // RNE
    return (u16)(u >> 16);
}
DEV float b2f(u16 h) { return __builtin_bit_cast(float, (unsigned)h << 16); }
DEV float silu_(float v) { return v / (1.f + __expf(-v)); }
DEV float b2f_lo(unsigned w) { return __builtin_bit_cast(float, w << 16); }
DEV float b2f_hi(unsigned w) { return __builtin_bit_cast(float, w & 0xffff0000u); }
DEV void unpack8(uint4 w, float* f) {
    f[0] = b2f_lo(w.x); f[1] = b2f_hi(w.x);
    f[2] = b2f_lo(w.y); f[3] = b2f_hi(w.y);
    f[4] = b2f_lo(w.z); f[5] = b2f_hi(w.z);
    f[6] = b2f_lo(w.w); f[7] = b2f_hi(w.w);
}

DEV void gload16(const void* g, void* l) {
    // async global->LDS, 16B/lane; LDS dest = wave-uniform base + lane*16
    __builtin_amdgcn_global_load_lds((const __attribute__((address_space(1))) unsigned int*)g,
                                     (__attribute__((address_space(3))) unsigned int*)l,
                                     16, 0, 0);
}

// ---------------- weight f32 -> bf16 ----------------
__global__ __launch_bounds__(256) void cvt_bf16_k(const float* __restrict__ in,
                                                  u16* __restrict__ out, int n4) {
    int i = blockIdx.x * 256 + threadIdx.x;
    if (i >= n4) return;
    float4 v = reinterpret_cast<const float4*>(in)[i];
    ushort4 o;
    o.x = f2b(v.x); o.y = f2b(v.y); o.z = f2b(v.z); o.w = f2b(v.w);
    reinterpret_cast<ushort4*>(out)[i] = o;
}

// ---------------- fused reduce: out = resid + p0 + p1 (partials bf16) ----------------
__global__ __launch_bounds__(256) void addred_k(const float* __restrict__ resid,
                                                const u16* __restrict__ p0,
                                                const u16* __restrict__ p1,
                                                float* __restrict__ out, int n4) {
    int i = blockIdx.x * 256 + threadIdx.x;
    if (i >= n4) return;
    float4 rv = reinterpret_cast<const float4*>(resid)[i];
    ushort4 a = reinterpret_cast<const ushort4*>(p0)[i];
    ushort4 b = reinterpret_cast<const ushort4*>(p1)[i];
    float4 o;
    o.x = rv.x + b2f(a.x) + b2f(b.x);
    o.y = rv.y + b2f(a.y) + b2f(b.y);
    o.z = rv.z + b2f(a.z) + b2f(b.z);
    o.w = rv.w + b2f(a.w) + b2f(b.w);
    reinterpret_cast<float4*>(out)[i] = o;
}

// ---------------- rmsnorm (D=1024), fp32 in -> bf16 out ----------------
__global__ __launch_bounds__(256) void rmsnorm_k(const float* __restrict__ x,
                                                 const float* __restrict__ w,
                                                 u16* __restrict__ out) {
    int row = blockIdx.x;
    int t = threadIdx.x;
    float4 v = reinterpret_cast<const float4*>(x + (size_t)row * 1024)[t];
    float s = v.x * v.x + v.y * v.y + v.z * v.z + v.w * v.w;
#pragma unroll
    for (int off = 32; off; off >>= 1) s += __shfl_xor(s, off);
    __shared__ float red[4];
    if ((t & 63) == 0) red[t >> 6] = s;
    __syncthreads();
    float tot = red[0] + red[1] + red[2] + red[3];
    float scale = rsqrtf(tot * (1.f / 1024.f) + 1e-6f);
    float4 wv = reinterpret_cast<const float4*>(w)[t];
    ushort4 o;
    o.x = f2b(v.x * wv.x * scale);
    o.y = f2b(v.y * wv.y * scale);
    o.z = f2b(v.z * wv.z * scale);
    o.w = f2b(v.w * wv.w * scale);
    reinterpret_cast<ushort4*>(out + (size_t)row * 1024)[t] = o;
}

// ---------------- GEMM: C[M,N] = A[M,K] * B[N,K]^T (bf16 in, fp32 acc) ----------------
// 128x128 tile, BK=32, 4 waves (2x2), each 64x64 via 4x4 x mfma_16x16x32_bf16.
// XCD-aware block swizzle (nwg must be %8==0 -- all our grids are).
// SPLIT: gridDim.z=2, z-th block handles K/2, stores bf16 partial at
//        C + z * (gridDim.x*128) * ldc.
// EPI: 0 = store bf16
//      1 = softplus(acc + bias[col]) -> bf16
//      2 = acc + residf32[row,col]   -> f32
//      4 = silu(auxbf16[row,col]) * acc -> bf16   (aux may alias C, same-idx only)
//      5 = dual store: col<2048 -> C[row*ldc+col], else aux[row*ldaux+col-2048]
template <int EPI, bool SPLIT = false>
__global__ __launch_bounds__(256) void gemm_bt(
    const u16* __restrict__ A, int lda,
    const u16* __restrict__ B, int ldb,
    void* C, int ldc,
    int N, int K,
    const float* __restrict__ bias,
    const void* aux, int ldaux) {
    __shared__ u16 lsA[128 * 32];
    __shared__ u16 lsB[128 * 32];
    const int t = threadIdx.x;
    const int l = t & 63, w = t >> 6;

    // XCD swizzle
    int nwg = gridDim.x * gridDim.y;
    int bid = blockIdx.y * gridDim.x + blockIdx.x;
    int cpx = nwg >> 3;
    int swz = (bid & 7) * cpx + (bid >> 3);
    const int m0 = (swz % gridDim.x) * 128, n0 = (swz / gridDim.x) * 128;

    int klo = 0, klen = K;
    if constexpr (SPLIT) { klen = K >> 1; klo = blockIdx.z * klen; }

    const int wm = w >> 1, wn = w & 1;
    const int lrow = l & 15, lk8 = (l >> 4) * 8;

    const int sr = w * 16 + (l >> 2);   // 0..63
    const int sc = (l & 3) * 8;         // 0,8,16,24
    const u16* gA0 = A + (size_t)(m0 + sr) * lda + sc + klo;
    const u16* gA1 = gA0 + (size_t)64 * lda;
    int nr0 = n0 + sr;      if (nr0 > N - 1) nr0 = N - 1;
    int nr1 = n0 + 64 + sr; if (nr1 > N - 1) nr1 = N - 1;
    const u16* gB0 = B + (size_t)nr0 * ldb + sc + klo;
    const u16* gB1 = B + (size_t)nr1 * ldb + sc + klo;
    u16* ldsA0 = &lsA[w * 512];
    u16* ldsA1 = &lsA[2048 + w * 512];
    u16* ldsB0 = &lsB[w * 512];
    u16* ldsB1 = &lsB[2048 + w * 512];

    f32x4 acc[4][4];
#pragma unroll
    for (int i = 0; i < 4; ++i)
#pragma unroll
        for (int j = 0; j < 4; ++j) acc[i][j] = (f32x4){0.f, 0.f, 0.f, 0.f};

    for (int k0 = 0; k0 < klen; k0 += 32) {
        gload16(gA0 + k0, ldsA0);
        gload16(gA1 + k0, ldsA1);
        gload16(gB0 + k0, ldsB0);
        gload16(gB1 + k0, ldsB1);
        __syncthreads();
        bf16x8 af[4], bfr[4];
#pragma unroll
        for (int i = 0; i < 4; ++i)
            af[i] = *reinterpret_cast<const bf16x8*>(&lsA[(wm * 64 + i * 16 + lrow) * 32 + lk8]);
#pragma unroll
        for (int j = 0; j < 4; ++j)
            bfr[j] = *reinterpret_cast<const bf16x8*>(&lsB[(wn * 64 + j * 16 + lrow) * 32 + lk8]);
#pragma unroll
        for (int i = 0; i < 4; ++i)
#pragma unroll
            for (int j = 0; j < 4; ++j)
                acc[i][j] = __builtin_amdgcn_mfma_f32_16x16x32_bf16(af[i], bfr[j], acc[i][j], 0, 0, 0);
        __syncthreads();
    }

    u16* Cp = (u16*)C;
    if constexpr (SPLIT)
        Cp += (size_t)blockIdx.z * gridDim.x * 128 * ldc;

    // C/D layout: col = lane&15, row = (lane>>4)*4 + reg
    const int rbase = m0 + wm * 64 + (l >> 4) * 4;
    const int cbase = n0 + wn * 64 + (l & 15);
#pragma unroll
    for (int i = 0; i < 4; ++i) {
#pragma unroll
        for (int j = 0; j < 4; ++j) {
            int col = cbase + j * 16;
            if (col >= N) continue;
#pragma unroll
            for (int r = 0; r < 4; ++r) {
                int row = rbase + i * 16 + r;
                float v = acc[i][j][r];
                size_t idx = (size_t)row * ldc + col;
                if constexpr (EPI == 0) {
                    Cp[idx] = f2b(v);
                } else if constexpr (EPI == 1) {
                    float z = v + bias[col];
                    float sp = z > 20.f ? z : log1pf(__expf(z));
                    Cp[idx] = f2b(sp);
                } else if constexpr (EPI == 2) {
                    ((float*)C)[idx] = v + ((const float*)aux)[(size_t)row * ldaux + col];
                } else if constexpr (EPI == 4) {
                    float g = b2f(((const u16*)aux)[(size_t)row * ldaux + col]);
                    Cp[idx] = f2b(silu_(g) * v);
                } else if constexpr (EPI == 5) {
                    if (col < 2048)
                        ((u16*)C)[(size_t)row * ldc + col] = f2b(v);
                    else
                        ((u16*)aux)[(size_t)row * ldaux + (col - 2048)] = f2b(v);
                }
            }
        }
    }
}

// ---------------- causal depthwise conv (width 4) + bias + silu ----------------
__global__ __launch_bounds__(256) void conv_k(const u16* __restrict__ xraw,
                                              const float* __restrict__ cw,
                                              const float* __restrict__ cb,
                                              u16* __restrict__ xin) {
    size_t idx = (size_t)blockIdx.x * 256 + threadIdx.x;
    if (idx >= (size_t)4096 * 2048) return;
    int d = (int)(idx & 2047);
    int m = (int)(idx >> 11);        // b*2048 + l
    int lpos = m & 2047, b = m >> 11;
    float acc = cb[d];
#pragma unroll
    for (int j = 0; j < 4; ++j) {
        int lj = lpos - 3 + j;
        if (lj >= 0)
            acc += b2f(xraw[((size_t)(b * 2048 + lj) << 11) + d]) * cw[d * 4 + j];
    }
    xin[idx] = f2b(silu_(acc));
}

// ---------------- chunked selective scan ----------------
// P1: per-chunk local scan (h starts at 0), emit final state + sum(delta).
__global__ __launch_bounds__(256) void scan_p1(const u16* __restrict__ dlt,
                                               const u16* __restrict__ xin,
                                               const u16* __restrict__ xdbl,
                                               const float* __restrict__ A_log,
                                               float* __restrict__ hfin,
                                               float* __restrict__ sdlt) {
    int blk = blockIdx.x;
    int g = blk & 7, c = (blk >> 3) & 31, b = blk >> 8;
    int d = g * 256 + threadIdx.x;
    __shared__ u16 bc[CHUNK * 32];
    {
        int i = threadIdx.x;
        int r = i >> 2, q = i & 3;
        const u16* src = xdbl + ((size_t)(b * 2048 + c * CHUNK + r) * 96 + 64 + q * 8);
        *reinterpret_cast<uint4*>(&bc[r * 32 + q * 8]) = *reinterpret_cast<const uint4*>(src);
    }
    __syncthreads();
    float A2[16];
#pragma unroll
    for (int n = 0; n < 16; ++n) A2[n] = -__expf(A_log[d * 16 + n]) * 1.44269504f;
    float h[16];
#pragma unroll
    for (int n = 0; n < 16; ++n) h[n] = 0.f;
    float S = 0.f;
    size_t base = ((size_t)(b * 2048 + c * CHUNK) << 11) + d;
#pragma unroll 4
    for (int t = 0; t < CHUNK; ++t) {
        float dl = b2f(dlt[base + ((size_t)t << 11)]);
        float xv = b2f(xin[base + ((size_t)t << 11)]);
        S += dl;
        float dx = dl * xv;
        float Bv[16];
        unpack8(*reinterpret_cast<const uint4*>(&bc[t * 32]), Bv);
        unpack8(*reinterpret_cast<const uint4*>(&bc[t * 32 + 8]), Bv + 8);
#pragma unroll
        for (int n = 0; n < 16; ++n)
            h[n] = __builtin_amdgcn_exp2f(dl * A2[n]) * h[n] + dx * Bv[n];
    }
    float* hf = hfin + ((size_t)((b * NCH + c) * 2048 + d) << 4);
#pragma unroll
    for (int n = 0; n < 4; ++n)
        reinterpret_cast<float4*>(hf)[n] = (float4){h[4*n], h[4*n+1], h[4*n+2], h[4*n+3]};
    sdlt[(b * NCH + c) * 2048 + d] = S;
}

// P2: carry propagation across chunks. thread = (b, d, n)
__global__ __launch_bounds__(256) void scan_p2(const float* __restrict__ hfin,
                                               const float* __restrict__ sdlt,
                                               const float* __restrict__ A_log,
                                               float* __restrict__ hini) {
    int t = blockIdx.x * 256 + threadIdx.x;
    int n = t & 15, d = (t >> 4) & 2047, b = t >> 15;
    float A2 = -__expf(A_log[d * 16 + n]) * 1.44269504f;
    float h = 0.f;
    for (int c = 0; c < NCH; ++c) {
        size_t idx = ((size_t)((b * NCH + c) * 2048 + d) << 4) + n;
        hini[idx] = h;
        float P = __builtin_amdgcn_exp2f(A2 * sdlt[(b * NCH + c) * 2048 + d]);
        h = P * h + hfin[idx];
    }
}

// P3: re-run chunks from propagated initial state; fuse y = sum(h*C) + x*D, * silu(z)
__global__ __launch_bounds__(256) void scan_p3(const u16* __restrict__ dlt,
                                               const u16* __restrict__ xin,
                                               const u16* __restrict__ xdbl,
                                               const u16* __restrict__ zb,
                                               const float* __restrict__ A_log,
                                               const float* __restrict__ Dv,
                                               const float* __restrict__ hini,
                                               u16* __restrict__ y2) {
    int blk = blockIdx.x;
    int g = blk & 7, c = (blk >> 3) & 31, b = blk >> 8;
    int d = g * 256 + threadIdx.x;
    __shared__ u16 bc[CHUNK * 32];
    {
        int i = threadIdx.x;
        int r = i >> 2, q = i & 3;
        const u16* src = xdbl + ((size_t)(b * 2048 + c * CHUNK + r) * 96 + 64 + q * 8);
        *reinterpret_cast<uint4*>(&bc[r * 32 + q * 8]) = *reinterpret_cast<const uint4*>(src);
    }
    __syncthreads();
    float A2[16];
#pragma unroll
    for (int n = 0; n < 16; ++n) A2[n] = -__expf(A_log[d * 16 + n]) * 1.44269504f;
    float h[16];
    const float* hi = hini + ((size_t)((b * NCH + c) * 2048 + d) << 4);
#pragma unroll
    for (int n = 0; n < 4; ++n) {
        float4 v = reinterpret_cast<const float4*>(hi)[n];
        h[4*n] = v.x; h[4*n+1] = v.y; h[4*n+2] = v.z; h[4*n+3] = v.w;
    }
    float Dd = Dv[d];
    size_t base = ((size_t)(b * 2048 + c * CHUNK) << 11) + d;
#pragma unroll 4
    for (int t = 0; t < CHUNK; ++t) {
        float dl = b2f(dlt[base + ((size_t)t << 11)]);
        float xv = b2f(xin[base + ((size_t)t << 11)]);
        float zv = b2f(zb[base + ((size_t)t << 11)]);
        float dx = dl * xv;
        float Bv[16], Cv[16];
        unpack8(*reinterpret_cast<const uint4*>(&bc[t * 32]), Bv);
        unpack8(*reinterpret_cast<const uint4*>(&bc[t * 32 + 8]), Bv + 8);
        unpack8(*reinterpret_cast<const uint4*>(&bc[t * 32 + 16]), Cv);
        unpack8(*reinterpret_cast<const uint4*>(&bc[t * 32 + 24]), Cv + 8);
        float y = 0.f;
#pragma unroll
        for (int n = 0; n < 16; ++n) {
            h[n] = __builtin_amdgcn_exp2f(dl * A2[n]) * h[n] + dx * Bv[n];
            y += h[n] * Cv[n];
        }
        y = (y + xv * Dd) * silu_(zv);
        y2[base + ((size_t)t << 11)] = f2b(y);
    }
}

// ---------------- launch ----------------
extern "C" void kernel_launch(void* const* d_in, const int* in_sizes, int n_in,
                              void* d_out, int out_size, void* d_ws, size_t ws_size,
                              hipStream_t stream) {
    const float* x         = (const float*)d_in[0];
    const float* n1w       = (const float*)d_in[1];
    const float* n2w       = (const float*)d_in[2];
    const float* w_inproj  = (const float*)d_in[3];
    const float* conv_w    = (const float*)d_in[4];
    const float* conv_b    = (const float*)d_in[5];
    const float* x_projw   = (const float*)d_in[6];
    const float* w_dtproj  = (const float*)d_in[7];
    const float* dt_b      = (const float*)d_in[8];
    const float* A_log     = (const float*)d_in[9];
    const float* Dv        = (const float*)d_in[10];
    const float* w_outproj = (const float*)d_in[11];
    const float* w1        = (const float*)d_in[12];
    const float* w3        = (const float*)d_in[13];
    const float* w2        = (const float*)d_in[14];

    // ---- workspace map (peak 85,196,800 B ~= 81.3 MiB) ----
    char* ws = (char*)d_ws;
    u16* wbuf    = (u16*)(ws + 0);          // 8 MiB weight scratch; hfin during scan
    u16* h_bf    = (u16*)(ws + 8388608);    // 4096x1024 bf16 (h1/h2); hini during scan
    u16* xraw_bf = (u16*)(ws + 16777216);   // 4096x2048 (pre-conv); later y2; later g1
    u16* z_bf    = (u16*)(ws + 33554432);   // 4096x2048 (gate); later out_proj partials
    u16* xin_bf  = (u16*)(ws + 50331648);   // 4096x2048; later w2 partials
    u16* dlt_bf  = (u16*)(ws + 67108864);   // 4096x2048; later x2_f (f32)
    u16* xdbl_bf = (u16*)(ws + 83886080);   // 4096x96 -> ends 84,672,512
    float* sdlt  = (float*)(ws + 84672512); // 512 KiB -> ends 85,196,800
    float* hfin  = (float*)wbuf;            // 8 MiB
    float* hini  = (float*)h_bf;            // 8 MiB (h1 dead during scan)
    u16* y2_bf   = xraw_bf;                 // xraw dead after conv
    float* x2_f  = (float*)(ws + 67108864); // dlt dead after scan
    u16* g1_bf   = xraw_bf;                 // y2 dead after out_proj; spans z region too
    u16* act_bf  = g1_bf;                   // in-place over g1 (EPI4 same-idx)
    u16* pOP     = z_bf;                    // out_proj partials: 2 x 4096x1024 bf16
    u16* pW2     = xin_bf;                  // w2 partials: 2 x 4096x1024 bf16
    const size_t PSTRIDE = (size_t)4096 * 1024;

    auto cvt = [&](const float* src, int n) {
        int n4 = n >> 2;
        cvt_bf16_k<<<(n4 + 255) / 256, 256, 0, stream>>>(src, wbuf, n4);
    };

    // h1 = rmsnorm(x)
    rmsnorm_k<<<4096, 256, 0, stream>>>(x, n1w, h_bf);
    // fused in_proj: [xraw | z] = h1 @ in_proj^T  (N=4096, dual-store epilogue)
    cvt(w_inproj, 4096 * 1024);
    gemm_bt<5><<<dim3(32, 32), 256, 0, stream>>>(h_bf, 1024, wbuf, 1024, xraw_bf, 2048,
                                                 4096, 1024, nullptr, z_bf, 2048);
    // xin = silu(causal_conv(xraw) + b)
    conv_k<<<32768, 256, 0, stream>>>(xraw_bf, conv_w, conv_b, xin_bf);
    // x_dbl = xin @ x_proj^T  (N=96, K=2048)
    cvt(x_projw, 96 * 2048);
    gemm_bt<0><<<dim3(32, 1), 256, 0, stream>>>(xin_bf, 2048, wbuf, 2048, xdbl_bf, 96,
                                                96, 2048, nullptr, nullptr, 0);
    // delta = softplus(x_dbl[:, :64] @ dt_proj^T + dt_b)  (N=2048, K=64)
    cvt(w_dtproj, 2048 * 64);
    gemm_bt<1><<<dim3(32, 16), 256, 0, stream>>>(xdbl_bf, 96, wbuf, 64, dlt_bf, 2048,
                                                 2048, 64, dt_b, nullptr, 0);
    // chunked selective scan -> y2 (overlays xraw)
    scan_p1<<<512, 256, 0, stream>>>(dlt_bf, xin_bf, xdbl_bf, A_log, hfin, sdlt);
    scan_p2<<<256, 256, 0, stream>>>(hfin, sdlt, A_log, hini);
    scan_p3<<<512, 256, 0, stream>>>(dlt_bf, xin_bf, xdbl_bf, z_bf, A_log, Dv, hini, y2_bf);
    // x2 = x + y2 @ out_proj^T  (N=1024, K=2048), split-K=2 single dispatch
    cvt(w_outproj, 1024 * 2048);
    gemm_bt<0, true><<<dim3(32, 8, 2), 256, 0, stream>>>(y2_bf, 2048, wbuf, 2048, pOP, 1024,
                                                         1024, 2048, nullptr, nullptr, 0);
    addred_k<<<4096, 256, 0, stream>>>(x, pOP, pOP + PSTRIDE, x2_f, 4096 * 1024 / 4);
    // h2 = rmsnorm(x2)
    rmsnorm_k<<<4096, 256, 0, stream>>>(x2_f, n2w, h_bf);
    // g1 = h2 @ w1^T ; act = silu(g1) * (h2 @ w3^T)   (act in-place over g1)
    cvt(w1, 4096 * 1024);
    gemm_bt<0><<<dim3(32, 32), 256, 0, stream>>>(h_bf, 1024, wbuf, 1024, g1_bf, 4096,
                                                 4096, 1024, nullptr, nullptr, 0);
    cvt(w3, 4096 * 1024);
    gemm_bt<4><<<dim3(32, 32), 256, 0, stream>>>(h_bf, 1024, wbuf, 1024, act_bf, 4096,
                                                 4096, 1024, nullptr, g1_bf, 4096);
    // out = x2 + act @ w2^T  (N=1024, K=4096), split-K=2 single dispatch
    cvt(w2, 1024 * 4096);
    gemm_bt<0, true><<<dim3(32, 8, 2), 256, 0, stream>>>(act_bf, 4096, wbuf, 4096, pW2, 1024,
                                                         1024, 4096, nullptr, nullptr, 0);
    addred_k<<<4096, 256, 0, stream>>>(x2_f, pW2, pW2 + PSTRIDE, (float*)d_out, 4096 * 1024 / 4);
}

// Round 7
// 702.923 us; speedup vs baseline: 3.0342x; 1.0041x over previous
//
#include <hip/hip_runtime.h>

#define DEV __device__ __forceinline__

typedef unsigned short u16;
typedef float f32x4 __attribute__((ext_vector_type(4)));
typedef __bf16 bf16x8 __attribute__((ext_vector_type(8)));

#define CHUNK 64
#define NCH 32   // 2048 / CHUNK

// ---------------- helpers ----------------
DEV u16 f2b(float f) {
    unsigned u = __builtin_bit_cast(unsigned, f);
    u += 0x7fffu + ((u >> 16) & 1u);   // RNE
    return (u16)(u >> 16);
}
DEV float b2f(u16 h) { return __builtin_bit_cast(float, (unsigned)h << 16); }
DEV float silu_(float v) { return v / (1.f + __expf(-v)); }
DEV float b2f_lo(unsigned w) { return __builtin_bit_cast(float, w << 16); }
DEV float b2f_hi(unsigned w) { return __builtin_bit_cast(float, w & 0xffff0000u); }
DEV void unpack8(uint4 w, float* f) {
    f[0] = b2f_lo(w.x); f[1] = b2f_hi(w.x);
    f[2] = b2f_lo(w.y); f[3] = b2f_hi(w.y);
    f[4] = b2f_lo(w.z); f[5] = b2f_hi(w.z);
    f[6] = b2f_lo(w.w); f[7] = b2f_hi(w.w);
}

DEV void gload16(const void* g, void* l) {
    // async global->LDS, 16B/lane; LDS dest = wave-uniform base + lane*16
    __builtin_amdgcn_global_load_lds((const __attribute__((address_space(1))) unsigned int*)g,
                                     (__attribute__((address_space(3))) unsigned int*)l,
                                     16, 0, 0);
}

// ---------------- weight f32 -> bf16 ----------------
__global__ __launch_bounds__(256) void cvt_bf16_k(const float* __restrict__ in,
                                                  u16* __restrict__ out, int n4) {
    int i = blockIdx.x * 256 + threadIdx.x;
    if (i >= n4) return;
    float4 v = reinterpret_cast<const float4*>(in)[i];
    ushort4 o;
    o.x = f2b(v.x); o.y = f2b(v.y); o.z = f2b(v.z); o.w = f2b(v.w);
    reinterpret_cast<ushort4*>(out)[i] = o;
}

// ---------------- fused reduce: out = resid + p0 + p1 (partials bf16) ----------------
__global__ __launch_bounds__(256) void addred_k(const float* __restrict__ resid,
                                                const u16* __restrict__ p0,
                                                const u16* __restrict__ p1,
                                                float* __restrict__ out, int n4) {
    int i = blockIdx.x * 256 + threadIdx.x;
    if (i >= n4) return;
    float4 rv = reinterpret_cast<const float4*>(resid)[i];
    ushort4 a = reinterpret_cast<const ushort4*>(p0)[i];
    ushort4 b = reinterpret_cast<const ushort4*>(p1)[i];
    float4 o;
    o.x = rv.x + b2f(a.x) + b2f(b.x);
    o.y = rv.y + b2f(a.y) + b2f(b.y);
    o.z = rv.z + b2f(a.z) + b2f(b.z);
    o.w = rv.w + b2f(a.w) + b2f(b.w);
    reinterpret_cast<float4*>(out)[i] = o;
}

// ---------------- rmsnorm (D=1024), fp32 in -> bf16 out ----------------
__global__ __launch_bounds__(256) void rmsnorm_k(const float* __restrict__ x,
                                                 const float* __restrict__ w,
                                                 u16* __restrict__ out) {
    int row = blockIdx.x;
    int t = threadIdx.x;
    float4 v = reinterpret_cast<const float4*>(x + (size_t)row * 1024)[t];
    float s = v.x * v.x + v.y * v.y + v.z * v.z + v.w * v.w;
#pragma unroll
    for (int off = 32; off; off >>= 1) s += __shfl_xor(s, off);
    __shared__ float red[4];
    if ((t & 63) == 0) red[t >> 6] = s;
    __syncthreads();
    float tot = red[0] + red[1] + red[2] + red[3];
    float scale = rsqrtf(tot * (1.f / 1024.f) + 1e-6f);
    float4 wv = reinterpret_cast<const float4*>(w)[t];
    ushort4 o;
    o.x = f2b(v.x * wv.x * scale);
    o.y = f2b(v.y * wv.y * scale);
    o.z = f2b(v.z * wv.z * scale);
    o.w = f2b(v.w * wv.w * scale);
    reinterpret_cast<ushort4*>(out + (size_t)row * 1024)[t] = o;
}

// ---------------- GEMM: C[M,N] = A[M,K] * B[N,K]^T (bf16 in, fp32 acc) ----------------
// 128x128 tile, BK=32, 4 waves (2x2), each 64x64 via 4x4 x mfma_16x16x32_bf16.
// 2-phase double-buffered LDS: STAGE(next) -> ds_read(cur)+MFMA -> one barrier
// (the __syncthreads drains vmcnt(0), so next tile is resident at loop top).
// XCD-aware block swizzle (nwg %8==0 for all our grids).
// NB=2: second B operand (B2), acc doubles; for fused w1/w3.
// SPLIT: gridDim.z=2, z-th block does K/2, bf16 partial at C + z*gridDim.x*128*ldc.
// EPI: 0 = store bf16
//      1 = softplus(acc + bias[col]) -> bf16
//      2 = acc + residf32[row,col]   -> f32
//      4 = silu(auxbf16[row,col]) * acc -> bf16
//      5 = dual store: col<2048 -> C, else aux[row*ldaux+col-2048]
//      6 = silu(acc0) * acc1 -> bf16 (NB=2)
template <int EPI, int NB = 1, bool SPLIT = false>
__global__ __launch_bounds__(256) void gemm_bt(
    const u16* __restrict__ A, int lda,
    const u16* __restrict__ B, int ldb,
    void* C, int ldc,
    int N, int K,
    const float* __restrict__ bias,
    const void* aux, int ldaux,
    const u16* __restrict__ B2) {
    __shared__ u16 lsA[2 * 4096];
    __shared__ u16 lsB[2 * 4096];
    __shared__ u16 lsB2[NB == 2 ? 2 * 4096 : 2];
    const int t = threadIdx.x;
    const int l = t & 63, w = t >> 6;

    // XCD swizzle
    int nwg = gridDim.x * gridDim.y;
    int bid = blockIdx.y * gridDim.x + blockIdx.x;
    int cpx = nwg >> 3;
    int swz = (bid & 7) * cpx + (bid >> 3);
    const int m0 = (swz % gridDim.x) * 128, n0 = (swz / gridDim.x) * 128;

    int klo = 0, klen = K;
    if constexpr (SPLIT) { klen = K >> 1; klo = blockIdx.z * klen; }

    const int wm = w >> 1, wn = w & 1;
    const int lrow = l & 15, lk8 = (l >> 4) * 8;

    const int sr = w * 16 + (l >> 2);   // 0..63
    const int sc = (l & 3) * 8;         // 0,8,16,24
    const u16* gA0 = A + (size_t)(m0 + sr) * lda + sc + klo;
    const u16* gA1 = gA0 + (size_t)64 * lda;
    int nr0 = n0 + sr;      if (nr0 > N - 1) nr0 = N - 1;
    int nr1 = n0 + 64 + sr; if (nr1 > N - 1) nr1 = N - 1;
    const u16* gB0 = B + (size_t)nr0 * ldb + sc + klo;
    const u16* gB1 = B + (size_t)nr1 * ldb + sc + klo;
    const u16* gB20 = nullptr;
    const u16* gB21 = nullptr;
    if constexpr (NB == 2) {
        gB20 = B2 + (size_t)nr0 * ldb + sc + klo;
        gB21 = B2 + (size_t)nr1 * ldb + sc + klo;
    }

    f32x4 acc[NB][4][4];
#pragma unroll
    for (int p = 0; p < NB; ++p)
#pragma unroll
        for (int i = 0; i < 4; ++i)
#pragma unroll
            for (int j = 0; j < 4; ++j) acc[p][i][j] = (f32x4){0.f, 0.f, 0.f, 0.f};

    auto stage = [&](int buf, int kt) {
        const int k0 = kt << 5;
        const int bo = buf << 12;
        gload16(gA0 + k0, &lsA[bo + w * 512]);
        gload16(gA1 + k0, &lsA[bo + 2048 + w * 512]);
        gload16(gB0 + k0, &lsB[bo + w * 512]);
        gload16(gB1 + k0, &lsB[bo + 2048 + w * 512]);
        if constexpr (NB == 2) {
            gload16(gB20 + k0, &lsB2[bo + w * 512]);
            gload16(gB21 + k0, &lsB2[bo + 2048 + w * 512]);
        }
    };

    const int nt = klen >> 5;
    stage(0, 0);
    __syncthreads();           // drains vmcnt(0): buf0 resident
    int cur = 0;
    for (int kt = 0; kt < nt; ++kt) {
        if (kt + 1 < nt) stage(cur ^ 1, kt + 1);   // overlap with compute below
        const int bo = cur << 12;
        bf16x8 af[4], bfr[4];
#pragma unroll
        for (int i = 0; i < 4; ++i)
            af[i] = *reinterpret_cast<const bf16x8*>(&lsA[bo + (wm * 64 + i * 16 + lrow) * 32 + lk8]);
#pragma unroll
        for (int j = 0; j < 4; ++j)
            bfr[j] = *reinterpret_cast<const bf16x8*>(&lsB[bo + (wn * 64 + j * 16 + lrow) * 32 + lk8]);
        if constexpr (NB == 2) {
            bf16x8 b2r[4];
#pragma unroll
            for (int j = 0; j < 4; ++j)
                b2r[j] = *reinterpret_cast<const bf16x8*>(&lsB2[bo + (wn * 64 + j * 16 + lrow) * 32 + lk8]);
#pragma unroll
            for (int i = 0; i < 4; ++i)
#pragma unroll
                for (int j = 0; j < 4; ++j) {
                    acc[0][i][j] = __builtin_amdgcn_mfma_f32_16x16x32_bf16(af[i], bfr[j], acc[0][i][j], 0, 0, 0);
                    acc[1][i][j] = __builtin_amdgcn_mfma_f32_16x16x32_bf16(af[i], b2r[j], acc[1][i][j], 0, 0, 0);
                }
        } else {
#pragma unroll
            for (int i = 0; i < 4; ++i)
#pragma unroll
                for (int j = 0; j < 4; ++j)
                    acc[0][i][j] = __builtin_amdgcn_mfma_f32_16x16x32_bf16(af[i], bfr[j], acc[0][i][j], 0, 0, 0);
        }
        __syncthreads();       // drains vmcnt(0) (next tile) + protects dbuf swap
        cur ^= 1;
    }

    u16* Cp = (u16*)C;
    if constexpr (SPLIT)
        Cp += (size_t)blockIdx.z * gridDim.x * 128 * ldc;

    // C/D layout: col = lane&15, row = (lane>>4)*4 + reg
    const int rbase = m0 + wm * 64 + (l >> 4) * 4;
    const int cbase = n0 + wn * 64 + (l & 15);
#pragma unroll
    for (int i = 0; i < 4; ++i) {
#pragma unroll
        for (int j = 0; j < 4; ++j) {
            int col = cbase + j * 16;
            if (col >= N) continue;
#pragma unroll
            for (int r = 0; r < 4; ++r) {
                int row = rbase + i * 16 + r;
                float v = acc[0][i][j][r];
                size_t idx = (size_t)row * ldc + col;
                if constexpr (EPI == 0) {
                    Cp[idx] = f2b(v);
                } else if constexpr (EPI == 1) {
                    float z = v + bias[col];
                    float sp = z > 20.f ? z : log1pf(__expf(z));
                    Cp[idx] = f2b(sp);
                } else if constexpr (EPI == 2) {
                    ((float*)C)[idx] = v + ((const float*)aux)[(size_t)row * ldaux + col];
                } else if constexpr (EPI == 4) {
                    float g = b2f(((const u16*)aux)[(size_t)row * ldaux + col]);
                    Cp[idx] = f2b(silu_(g) * v);
                } else if constexpr (EPI == 5) {
                    if (col < 2048)
                        ((u16*)C)[(size_t)row * ldc + col] = f2b(v);
                    else
                        ((u16*)aux)[(size_t)row * ldaux + (col - 2048)] = f2b(v);
                } else if constexpr (EPI == 6) {
                    Cp[idx] = f2b(silu_(v) * acc[NB - 1][i][j][r]);
                }
            }
        }
    }
}

// ---------------- causal depthwise conv (width 4) + bias + silu ----------------
__global__ __launch_bounds__(256) void conv_k(const u16* __restrict__ xraw,
                                              const float* __restrict__ cw,
                                              const float* __restrict__ cb,
                                              u16* __restrict__ xin) {
    size_t idx = (size_t)blockIdx.x * 256 + threadIdx.x;
    if (idx >= (size_t)4096 * 2048) return;
    int d = (int)(idx & 2047);
    int m = (int)(idx >> 11);        // b*2048 + l
    int lpos = m & 2047, b = m >> 11;
    float acc = cb[d];
#pragma unroll
    for (int j = 0; j < 4; ++j) {
        int lj = lpos - 3 + j;
        if (lj >= 0)
            acc += b2f(xraw[((size_t)(b * 2048 + lj) << 11) + d]) * cw[d * 4 + j];
    }
    xin[idx] = f2b(silu_(acc));
}

// ---------------- chunked selective scan ----------------
__global__ __launch_bounds__(256) void scan_p1(const u16* __restrict__ dlt,
                                               const u16* __restrict__ xin,
                                               const u16* __restrict__ xdbl,
                                               const float* __restrict__ A_log,
                                               float* __restrict__ hfin,
                                               float* __restrict__ sdlt) {
    int blk = blockIdx.x;
    int g = blk & 7, c = (blk >> 3) & 31, b = blk >> 8;
    int d = g * 256 + threadIdx.x;
    __shared__ u16 bc[CHUNK * 32];
    {
        int i = threadIdx.x;
        int r = i >> 2, q = i & 3;
        const u16* src = xdbl + ((size_t)(b * 2048 + c * CHUNK + r) * 96 + 64 + q * 8);
        *reinterpret_cast<uint4*>(&bc[r * 32 + q * 8]) = *reinterpret_cast<const uint4*>(src);
    }
    __syncthreads();
    float A2[16];
#pragma unroll
    for (int n = 0; n < 16; ++n) A2[n] = -__expf(A_log[d * 16 + n]) * 1.44269504f;
    float h[16];
#pragma unroll
    for (int n = 0; n < 16; ++n) h[n] = 0.f;
    float S = 0.f;
    size_t base = ((size_t)(b * 2048 + c * CHUNK) << 11) + d;
#pragma unroll 4
    for (int t = 0; t < CHUNK; ++t) {
        float dl = b2f(dlt[base + ((size_t)t << 11)]);
        float xv = b2f(xin[base + ((size_t)t << 11)]);
        S += dl;
        float dx = dl * xv;
        float Bv[16];
        unpack8(*reinterpret_cast<const uint4*>(&bc[t * 32]), Bv);
        unpack8(*reinterpret_cast<const uint4*>(&bc[t * 32 + 8]), Bv + 8);
#pragma unroll
        for (int n = 0; n < 16; ++n)
            h[n] = __builtin_amdgcn_exp2f(dl * A2[n]) * h[n] + dx * Bv[n];
    }
    float* hf = hfin + ((size_t)((b * NCH + c) * 2048 + d) << 4);
#pragma unroll
    for (int n = 0; n < 4; ++n)
        reinterpret_cast<float4*>(hf)[n] = (float4){h[4*n], h[4*n+1], h[4*n+2], h[4*n+3]};
    sdlt[(b * NCH + c) * 2048 + d] = S;
}

__global__ __launch_bounds__(256) void scan_p2(const float* __restrict__ hfin,
                                               const float* __restrict__ sdlt,
                                               const float* __restrict__ A_log,
                                               float* __restrict__ hini) {
    int t = blockIdx.x * 256 + threadIdx.x;
    int n = t & 15, d = (t >> 4) & 2047, b = t >> 15;
    float A2 = -__expf(A_log[d * 16 + n]) * 1.44269504f;
    float h = 0.f;
    for (int c = 0; c < NCH; ++c) {
        size_t idx = ((size_t)((b * NCH + c) * 2048 + d) << 4) + n;
        hini[idx] = h;
        float P = __builtin_amdgcn_exp2f(A2 * sdlt[(b * NCH + c) * 2048 + d]);
        h = P * h + hfin[idx];
    }
}

__global__ __launch_bounds__(256) void scan_p3(const u16* __restrict__ dlt,
                                               const u16* __restrict__ xin,
                                               const u16* __restrict__ xdbl,
                                               const u16* __restrict__ zb,
                                               const float* __restrict__ A_log,
                                               const float* __restrict__ Dv,
                                               const float* __restrict__ hini,
                                               u16* __restrict__ y2) {
    int blk = blockIdx.x;
    int g = blk & 7, c = (blk >> 3) & 31, b = blk >> 8;
    int d = g * 256 + threadIdx.x;
    __shared__ u16 bc[CHUNK * 32];
    {
        int i = threadIdx.x;
        int r = i >> 2, q = i & 3;
        const u16* src = xdbl + ((size_t)(b * 2048 + c * CHUNK + r) * 96 + 64 + q * 8);
        *reinterpret_cast<uint4*>(&bc[r * 32 + q * 8]) = *reinterpret_cast<const uint4*>(src);
    }
    __syncthreads();
    float A2[16];
#pragma unroll
    for (int n = 0; n < 16; ++n) A2[n] = -__expf(A_log[d * 16 + n]) * 1.44269504f;
    float h[16];
    const float* hi = hini + ((size_t)((b * NCH + c) * 2048 + d) << 4);
#pragma unroll
    for (int n = 0; n < 4; ++n) {
        float4 v = reinterpret_cast<const float4*>(hi)[n];
        h[4*n] = v.x; h[4*n+1] = v.y; h[4*n+2] = v.z; h[4*n+3] = v.w;
    }
    float Dd = Dv[d];
    size_t base = ((size_t)(b * 2048 + c * CHUNK) << 11) + d;
#pragma unroll 4
    for (int t = 0; t < CHUNK; ++t) {
        float dl = b2f(dlt[base + ((size_t)t << 11)]);
        float xv = b2f(xin[base + ((size_t)t << 11)]);
        float zv = b2f(zb[base + ((size_t)t << 11)]);
        float dx = dl * xv;
        float Bv[16], Cv[16];
        unpack8(*reinterpret_cast<const uint4*>(&bc[t * 32]), Bv);
        unpack8(*reinterpret_cast<const uint4*>(&bc[t * 32 + 8]), Bv + 8);
        unpack8(*reinterpret_cast<const uint4*>(&bc[t * 32 + 16]), Cv);
        unpack8(*reinterpret_cast<const uint4*>(&bc[t * 32 + 24]), Cv + 8);
        float y = 0.f;
#pragma unroll
        for (int n = 0; n < 16; ++n) {
            h[n] = __builtin_amdgcn_exp2f(dl * A2[n]) * h[n] + dx * Bv[n];
            y += h[n] * Cv[n];
        }
        y = (y + xv * Dd) * silu_(zv);
        y2[base + ((size_t)t << 11)] = f2b(y);
    }
}

// ---------------- launch ----------------
extern "C" void kernel_launch(void* const* d_in, const int* in_sizes, int n_in,
                              void* d_out, int out_size, void* d_ws, size_t ws_size,
                              hipStream_t stream) {
    const float* x         = (const float*)d_in[0];
    const float* n1w       = (const float*)d_in[1];
    const float* n2w       = (const float*)d_in[2];
    const float* w_inproj  = (const float*)d_in[3];
    const float* conv_w    = (const float*)d_in[4];
    const float* conv_b    = (const float*)d_in[5];
    const float* x_projw   = (const float*)d_in[6];
    const float* w_dtproj  = (const float*)d_in[7];
    const float* dt_b      = (const float*)d_in[8];
    const float* A_log     = (const float*)d_in[9];
    const float* Dv        = (const float*)d_in[10];
    const float* w_outproj = (const float*)d_in[11];
    const float* w1        = (const float*)d_in[12];
    const float* w3        = (const float*)d_in[13];
    const float* w2        = (const float*)d_in[14];

    // ---- workspace map (peak 85,196,800 B ~= 81.3 MiB) ----
    char* ws = (char*)d_ws;
    u16* wbuf    = (u16*)(ws + 0);          // 8 MiB weight scratch; hfin during scan
    u16* h_bf    = (u16*)(ws + 8388608);    // 4096x1024 bf16 (h1/h2); hini during scan
    u16* xraw_bf = (u16*)(ws + 16777216);   // 4096x2048 (pre-conv); later y2; later act (32MB)
    u16* z_bf    = (u16*)(ws + 33554432);   // 4096x2048 (gate); later out_proj partials
    u16* xin_bf  = (u16*)(ws + 50331648);   // 4096x2048; later w3 bf16 copy, then w2 partials
    u16* dlt_bf  = (u16*)(ws + 67108864);   // 4096x2048; later x2_f (f32)
    u16* xdbl_bf = (u16*)(ws + 83886080);   // 4096x96 -> ends 84,672,512
    float* sdlt  = (float*)(ws + 84672512); // 512 KiB -> ends 85,196,800
    float* hfin  = (float*)wbuf;            // 8 MiB
    float* hini  = (float*)h_bf;            // 8 MiB (h1 dead during scan)
    u16* y2_bf   = xraw_bf;                 // xraw dead after conv
    float* x2_f  = (float*)(ws + 67108864); // dlt dead after scan
    u16* act_bf  = xraw_bf;                 // 4096x4096: y2 dead after out_proj, z dead after addred
    u16* wbuf3   = xin_bf;                  // w3 bf16 (8 MiB), xin dead after scan
    u16* pOP     = z_bf;                    // out_proj partials: 2 x 4096x1024 bf16
    u16* pW2     = xin_bf;                  // w2 partials: 2 x 4096x1024 bf16 (wbuf3 dead)
    const size_t PSTRIDE = (size_t)4096 * 1024;

    auto cvt = [&](const float* src, u16* dst, int n) {
        int n4 = n >> 2;
        cvt_bf16_k<<<(n4 + 255) / 256, 256, 0, stream>>>(src, dst, n4);
    };

    // h1 = rmsnorm(x)
    rmsnorm_k<<<4096, 256, 0, stream>>>(x, n1w, h_bf);
    // fused in_proj: [xraw | z] = h1 @ in_proj^T  (N=4096, dual-store epilogue)
    cvt(w_inproj, wbuf, 4096 * 1024);
    gemm_bt<5><<<dim3(32, 32), 256, 0, stream>>>(h_bf, 1024, wbuf, 1024, xraw_bf, 2048,
                                                 4096, 1024, nullptr, z_bf, 2048, nullptr);
    // xin = silu(causal_conv(xraw) + b)
    conv_k<<<32768, 256, 0, stream>>>(xraw_bf, conv_w, conv_b, xin_bf);
    // x_dbl = xin @ x_proj^T  (N=96, K=2048)
    cvt(x_projw, wbuf, 96 * 2048);
    gemm_bt<0><<<dim3(32, 1), 256, 0, stream>>>(xin_bf, 2048, wbuf, 2048, xdbl_bf, 96,
                                                96, 2048, nullptr, nullptr, 0, nullptr);
    // delta = softplus(x_dbl[:, :64] @ dt_proj^T + dt_b)  (N=2048, K=64)
    cvt(w_dtproj, wbuf, 2048 * 64);
    gemm_bt<1><<<dim3(32, 16), 256, 0, stream>>>(xdbl_bf, 96, wbuf, 64, dlt_bf, 2048,
                                                 2048, 64, dt_b, nullptr, 0, nullptr);
    // chunked selective scan -> y2 (overlays xraw)
    scan_p1<<<512, 256, 0, stream>>>(dlt_bf, xin_bf, xdbl_bf, A_log, hfin, sdlt);
    scan_p2<<<256, 256, 0, stream>>>(hfin, sdlt, A_log, hini);
    scan_p3<<<512, 256, 0, stream>>>(dlt_bf, xin_bf, xdbl_bf, z_bf, A_log, Dv, hini, y2_bf);
    // x2 = x + y2 @ out_proj^T  (N=1024, K=2048), split-K=2 single dispatch
    cvt(w_outproj, wbuf, 1024 * 2048);
    gemm_bt<0, 1, true><<<dim3(32, 8, 2), 256, 0, stream>>>(y2_bf, 2048, wbuf, 2048, pOP, 1024,
                                                            1024, 2048, nullptr, nullptr, 0, nullptr);
    addred_k<<<4096, 256, 0, stream>>>(x, pOP, pOP + PSTRIDE, x2_f, 4096 * 1024 / 4);
    // h2 = rmsnorm(x2)
    rmsnorm_k<<<4096, 256, 0, stream>>>(x2_f, n2w, h_bf);
    // act = silu(h2 @ w1^T) * (h2 @ w3^T)   -- single fused NB=2 dispatch
    cvt(w1, wbuf, 4096 * 1024);
    cvt(w3, wbuf3, 4096 * 1024);
    gemm_bt<6, 2><<<dim3(32, 32), 256, 0, stream>>>(h_bf, 1024, wbuf, 1024, act_bf, 4096,
                                                    4096, 1024, nullptr, nullptr, 0, wbuf3);
    // out = x2 + act @ w2^T  (N=1024, K=4096), split-K=2 single dispatch
    cvt(w2, wbuf, 1024 * 4096);
    gemm_bt<0, 1, true><<<dim3(32, 8, 2), 256, 0, stream>>>(act_bf, 4096, wbuf, 4096, pW2, 1024,
                                                            1024, 4096, nullptr, nullptr, 0, nullptr);
    addred_k<<<4096, 256, 0, stream>>>(x2_f, pW2, pW2 + PSTRIDE, (float*)d_out, 4096 * 1024 / 4);
}